// Round 2
// baseline (75.905 us; speedup 1.0000x reference)
//
#include <hip/hip_runtime.h>

// Problem constants
#define B_    16
#define N1_   32
#define NL_   256
#define DM_   16   // d_model
#define A_    2    // heads
#define DK_   8
#define DV_   8
#define DOUT_ 16

#define NBN   (B_ * N1_)          // 512 blocks
#define PROJ_ELEMS (NBN * NL_ * DOUT_)   // 2097152
#define ZT    32                  // attn_mean staging tile width
#define ATP   33                  // padded stride (bank = (k+z)%32 -> 2-way, free)

__global__ __launch_bounds__(256, 2)
void mha_relu_kernel(const float* __restrict__ Q,
                     const float* __restrict__ K,
                     const float* __restrict__ V,
                     const float* __restrict__ Wq,
                     const float* __restrict__ Wk,
                     const float* __restrict__ Wv,
                     const float* __restrict__ Wo,
                     float* __restrict__ proj_out,
                     float* __restrict__ attn_out)
{
    __shared__ float sWq[DM_ * A_ * DK_];   // 256
    __shared__ float sWk[DM_ * A_ * DK_];   // 256
    __shared__ float sWv[DM_ * A_ * DV_];   // 256
    __shared__ float sWo[DV_ * A_ * DOUT_]; // 256
    __shared__ float KP[NL_ * 16];          // Kp[z][a*8+j]
    __shared__ float VP[NL_ * 16];          // Vp[z][a*8+m]
    __shared__ float AT[NL_ * ATP];         // attn_mean staging tile [256][33]

    const int tid = threadIdx.x;
    const int bn  = blockIdx.x;
    const int k   = tid;                    // this thread owns output row k

    // ---- load weights to LDS (each thread one element of each) ----
    sWq[tid] = Wq[tid];
    sWk[tid] = Wk[tid];
    sWv[tid] = Wv[tid];
    sWo[tid] = Wo[tid];
    __syncthreads();

    const size_t inoff = (size_t)bn * NL_ * DM_;   // row-block base for Q/K/V

    // ---- per-row projections ----
    // Qp[a*8+j] = sum_i Q[k,i] * Wq[i,a,j]   (kept in registers)
    // Kp, Vp    -> LDS (each thread computes its own row z = k)
    float Qp[16];
    float rowbuf[16];

    // Q row -> Qp (registers)
    {
        const float4* p = (const float4*)(Q + inoff + (size_t)k * DM_);
        #pragma unroll
        for (int i = 0; i < 4; ++i) {
            float4 t = p[i];
            rowbuf[4*i+0] = t.x; rowbuf[4*i+1] = t.y;
            rowbuf[4*i+2] = t.z; rowbuf[4*i+3] = t.w;
        }
        #pragma unroll
        for (int t = 0; t < 16; ++t) Qp[t] = 0.f;
        #pragma unroll
        for (int i = 0; i < 16; ++i) {
            float qi = rowbuf[i];
            #pragma unroll
            for (int t = 0; t < 16; ++t) Qp[t] += qi * sWq[i*16 + t];
        }
    }
    // K row -> KP LDS
    {
        const float4* p = (const float4*)(K + inoff + (size_t)k * DM_);
        #pragma unroll
        for (int i = 0; i < 4; ++i) {
            float4 t = p[i];
            rowbuf[4*i+0] = t.x; rowbuf[4*i+1] = t.y;
            rowbuf[4*i+2] = t.z; rowbuf[4*i+3] = t.w;
        }
        float acc[16];
        #pragma unroll
        for (int t = 0; t < 16; ++t) acc[t] = 0.f;
        #pragma unroll
        for (int i = 0; i < 16; ++i) {
            float ki = rowbuf[i];
            #pragma unroll
            for (int t = 0; t < 16; ++t) acc[t] += ki * sWk[i*16 + t];
        }
        #pragma unroll
        for (int t = 0; t < 16; ++t) KP[k*16 + t] = acc[t];
    }
    // V row -> VP LDS
    {
        const float4* p = (const float4*)(V + inoff + (size_t)k * DM_);
        #pragma unroll
        for (int i = 0; i < 4; ++i) {
            float4 t = p[i];
            rowbuf[4*i+0] = t.x; rowbuf[4*i+1] = t.y;
            rowbuf[4*i+2] = t.z; rowbuf[4*i+3] = t.w;
        }
        float acc[16];
        #pragma unroll
        for (int t = 0; t < 16; ++t) acc[t] = 0.f;
        #pragma unroll
        for (int i = 0; i < 16; ++i) {
            float vi = rowbuf[i];
            #pragma unroll
            for (int t = 0; t < 16; ++t) acc[t] += vi * sWv[i*16 + t];
        }
        #pragma unroll
        for (int t = 0; t < 16; ++t) VP[k*16 + t] = acc[t];
    }
    __syncthreads();

    // ---- main loop over z, tiled by ZT for coalesced attn_mean stores ----
    float emb[16];                          // emb[a*8+m]
    #pragma unroll
    for (int t = 0; t < 16; ++t) emb[t] = 0.f;

    float* atrow = &AT[k * ATP];
    float* aout  = attn_out + (size_t)bn * NL_ * NL_;

    for (int tile = 0; tile < NL_ / ZT; ++tile) {
        const int z0 = tile * ZT;

        #pragma unroll 8
        for (int zt = 0; zt < ZT; ++zt) {
            const int z = z0 + zt;
            // broadcast reads (uniform address across wave): conflict-free
            const float4* kpv = (const float4*)&KP[z * 16];
            float kp[16];
            #pragma unroll
            for (int i = 0; i < 4; ++i) {
                float4 t = kpv[i];
                kp[4*i+0] = t.x; kp[4*i+1] = t.y;
                kp[4*i+2] = t.z; kp[4*i+3] = t.w;
            }
            float s0 = 0.f, s1 = 0.f;
            #pragma unroll
            for (int j = 0; j < 8; ++j) {
                s0 += Qp[j]     * kp[j];
                s1 += Qp[8 + j] * kp[8 + j];
            }
            s0 = fmaxf(s0, 0.f);            // ReLU
            s1 = fmaxf(s1, 0.f);
            atrow[zt] = 0.5f * (s0 + s1);   // mean over heads

            const float4* vpv = (const float4*)&VP[z * 16];
            float vp[16];
            #pragma unroll
            for (int i = 0; i < 4; ++i) {
                float4 t = vpv[i];
                vp[4*i+0] = t.x; vp[4*i+1] = t.y;
                vp[4*i+2] = t.z; vp[4*i+3] = t.w;
            }
            #pragma unroll
            for (int t = 0; t < 8; ++t) {
                emb[t]     += s0 * vp[t];
                emb[8 + t] += s1 * vp[8 + t];
            }
        }
        __syncthreads();   // AT tile complete

        // cooperative coalesced store of the [256][ZT] tile
        #pragma unroll
        for (int i = 0; i < (NL_ * ZT) / 256; ++i) {
            const int idx = i * 256 + tid;
            const int row = idx >> 5;       // /32
            const int col = idx & 31;
            aout[(size_t)row * NL_ + z0 + col] = AT[row * ATP + col];
        }
        __syncthreads();   // AT free for next tile
    }

    // ---- output projection: proj[o] = sum_{a,m} emb[a*8+m] * Wo[m,a,o] ----
    float pr[16];
    #pragma unroll
    for (int o = 0; o < 16; ++o) pr[o] = 0.f;
    #pragma unroll
    for (int a = 0; a < 2; ++a) {
        #pragma unroll
        for (int m = 0; m < 8; ++m) {
            const float e = emb[a*8 + m];
            #pragma unroll
            for (int o = 0; o < 16; ++o) pr[o] += e * sWo[m*32 + a*16 + o];
        }
    }
    float4* po = (float4*)(proj_out + (size_t)bn * NL_ * DOUT_ + (size_t)k * DOUT_);
    po[0] = make_float4(pr[0],  pr[1],  pr[2],  pr[3]);
    po[1] = make_float4(pr[4],  pr[5],  pr[6],  pr[7]);
    po[2] = make_float4(pr[8],  pr[9],  pr[10], pr[11]);
    po[3] = make_float4(pr[12], pr[13], pr[14], pr[15]);
}

extern "C" void kernel_launch(void* const* d_in, const int* in_sizes, int n_in,
                              void* d_out, int out_size, void* d_ws, size_t ws_size,
                              hipStream_t stream) {
    const float* Q  = (const float*)d_in[0];
    const float* K  = (const float*)d_in[1];
    const float* V  = (const float*)d_in[2];
    const float* Wq = (const float*)d_in[3];
    const float* Wk = (const float*)d_in[4];
    const float* Wv = (const float*)d_in[5];
    const float* Wo = (const float*)d_in[6];

    float* proj = (float*)d_out;                 // [B,N1,NL,DOUT] = 2097152 floats
    float* attn = (float*)d_out + PROJ_ELEMS;    // [B,N1,NL,NL]

    mha_relu_kernel<<<NBN, 256, 0, stream>>>(Q, K, V, Wq, Wk, Wv, Wo, proj, attn);
}